// Round 7
// baseline (681.528 us; speedup 1.0000x reference)
//
#include <hip/hip_runtime.h>
#include <hip/hip_fp16.h>
#include <math.h>

// Problem constants: F_IN=64, K=16, C=20, L=4, H1=20, H2=2
// N=100k nodes, E=1.6M undirected edges, M=2E=3.2M directed entries.
//
// R6 lessons: capacity-bucket CSR build works (no more atomic floor);
// filter is LDS-issue bound (wave-uniform weight reads) -> 2 edges/thread
// shares every weight read; gather1 is dependent-load latency bound ->
// 4-edge ILP doubles memory-level parallelism.

#define SHIFT   7
#define NB_MAX  1024
#define CHUNKB  6144
#define BCAP    4608

// ---------------- K1: filter nets (analytic conv), TWO edges per thread ---------
__global__ __launch_bounds__(256) void filter_kernel(
    const float* __restrict__ attr, const float* __restrict__ cutoffs,
    const float* __restrict__ cw1, const float* __restrict__ cb1,
    const float* __restrict__ f1w1, const float* __restrict__ f1b1,
    const float* __restrict__ f2w1, const float* __restrict__ f2b1,
    const float* __restrict__ cw2, const float* __restrict__ cb2,
    const float* __restrict__ f1w2, const float* __restrict__ f1b2,
    const float* __restrict__ f2w2, const float* __restrict__ f2b2,
    float* __restrict__ wedge1, float* __restrict__ wedge2, int E)
{
    __shared__ float s_cut[16];
    __shared__ float s_w[2][344]; // cw(120) cb(20) f1w(160) f1b(8) f2w(32) f2b(4)
    __shared__ float tab[2 * 20 * 64];
    int tid = threadIdx.x;
    if (tid < 16) s_cut[tid] = cutoffs[tid];
    for (int i = tid; i < 344; i += 256) {
        float v1, v2;
        if (i < 120)      { v1 = cw1[i];       v2 = cw2[i]; }
        else if (i < 140) { v1 = cb1[i-120];   v2 = cb2[i-120]; }
        else if (i < 300) { v1 = f1w1[i-140];  v2 = f1w2[i-140]; }
        else if (i < 308) { v1 = f1b1[i-300];  v2 = f1b2[i-300]; }
        else if (i < 340) { v1 = f2w1[i-308];  v2 = f2w2[i-308]; }
        else              { v1 = f2b1[i-340];  v2 = f2b2[i-340]; }
        s_w[0][i] = v1; s_w[1][i] = v2;
    }
    __syncthreads();
    if (tid < 40) {
        int l = tid / 20, ch = tid % 20;
        const float* W = s_w[l];
        float w00 = W[ch*6+0], w01 = W[ch*6+1], w02 = W[ch*6+2];
        float w10 = W[ch*6+3], w11 = W[ch*6+4], w12 = W[ch*6+5];
        float b = W[120 + ch];
        float* tb = &tab[(l*20 + ch) * 64];
        tb[0]  = w01*s_cut[0]  + w02*s_cut[1];
        for (int k = 1; k <= 14; ++k)
            tb[k] = w00*s_cut[k-1] + w01*s_cut[k] + w02*s_cut[k+1];
        tb[15] = w00*s_cut[14] + w01*s_cut[15];
        float pm = tb[1]; tb[16+1] = pm;
        for (int j = 2; j <= 14; ++j) { pm = fminf(pm, tb[j]); tb[16+j] = pm; }
        float qm = tb[14]; tb[32+14] = qm;
        for (int j = 13; j >= 1; --j) { qm = fminf(qm, tb[j]); tb[32+j] = qm; }
        tb[48] = w00 + w01 + w02;
        tb[49] = w01 + w02;
        tb[50] = w00 + w01;
        tb[51] = w10 + w11 + w12;
        tb[52] = w10 + w11;
        tb[53] = w10;
        tb[54] = w11;
        tb[55] = w12;
        tb[56] = b;
    }
    __syncthreads();
    int Eh = (E + 1) >> 1;
    int t = blockIdx.x * 256 + tid;
    if (t >= Eh) return;
    int e1 = t, e2 = t + Eh;
    bool has2 = (e2 < E);

    float aa[2];
    int ii[2];
    aa[0] = attr[e1];
    aa[1] = has2 ? attr[e2] : aa[0];
    #pragma unroll
    for (int p = 0; p < 2; ++p) {
        int idx = 0;
        #pragma unroll
        for (int k = 0; k < 16; ++k) idx += (aa[p] > s_cut[k]) ? 1 : 0;
        ii[p] = idx;
    }

    #pragma unroll
    for (int layer = 0; layer < 2; ++layer) {
        const float* W = s_w[layer];
        float h[2][20];
        #pragma unroll
        for (int c = 0; c < 20; ++c) {
            const float* tb = &tab[(layer*20 + c) * 64];
            // shared table loads
            float b    = tb[56];
            float S    = tb[48], Sd0 = tb[49], S15 = tb[50];
            float W3   = tb[51], W2  = tb[52];
            float w10v = tb[53], w11v = tb[54], w12v = tb[55];
            float T0 = tb[0], T15 = tb[15];
            #pragma unroll
            for (int p = 0; p < 2; ++p) {
                float a = aa[p];
                int idx = ii[p];
                float base = fmaf(S, a, b);
                float y0 = fmaf(Sd0, a, b) - T0;
                y0 += (idx >= 1 ? w11v : 0.f) + (idx >= 2 ? w12v : 0.f);
                float m = y0;
                float y15 = fmaf(S15, a, b) - T15;
                y15 += (idx >= 15 ? w10v : 0.f) + (idx >= 16 ? w11v : 0.f);
                m = fmaxf(m, y15);
                {
                    int j = idx - 2; j = j > 14 ? 14 : j;
                    float v = base + W3 - tb[16 + j];
                    m = (idx >= 3) ? fmaxf(m, v) : m;
                }
                {
                    float v = base + W2 - tb[(idx >= 2 && idx <= 15) ? (idx-1) : 1];
                    m = (idx >= 2 && idx <= 15) ? fmaxf(m, v) : m;
                }
                {
                    float v = base + w10v - tb[(idx >= 1 && idx <= 14) ? idx : 1];
                    m = (idx >= 1 && idx <= 14) ? fmaxf(m, v) : m;
                }
                {
                    int j = idx + 1; j = j < 1 ? 1 : j;
                    float v = base - tb[32 + (j > 14 ? 14 : j)];
                    m = (idx <= 13) ? fmaxf(m, v) : m;
                }
                h[p][c] = fmaxf(m, 0.f);
            }
        }
        float g[2][8];
        #pragma unroll
        for (int j = 0; j < 8; ++j) {
            float bj = W[300 + j];
            float t1 = bj, t2 = bj;
            #pragma unroll
            for (int c = 0; c < 20; ++c) {
                float wj = W[140 + j*20 + c];
                t1 += wj * h[0][c];
                t2 += wj * h[1][c];
            }
            g[0][j] = fmaxf(t1, 0.f);
            g[1][j] = fmaxf(t2, 0.f);
        }
        float4 wo1, wo2;
        float* wp1 = (float*)&wo1;
        float* wp2 = (float*)&wo2;
        #pragma unroll
        for (int l = 0; l < 4; ++l) {
            float bl = W[340 + l];
            float t1 = bl, t2 = bl;
            #pragma unroll
            for (int j = 0; j < 8; ++j) {
                float wl = W[308 + l*8 + j];
                t1 += wl * g[0][j];
                t2 += wl * g[1][j];
            }
            wp1[l] = fmaxf(t1, 0.f);
            wp2[l] = fmaxf(t2, 0.f);
        }
        float4* dstp = (float4*)(layer == 0 ? wedge1 : wedge2);
        dstp[e1] = wo1;
        if (has2) dstp[e2] = wo2;
    }
}

// ---------------- K2: init bucket cursors to capacity bases ---------------------
__global__ __launch_bounds__(256) void init_bcur_kernel(int* __restrict__ bcur, int NB)
{
    int b = blockIdx.x * 256 + threadIdx.x;
    if (b < NB) bcur[b] = b * BCAP;
}

// ---------------- K3: scatter directed entries into capacity buckets ------------
// entry.x = nbr node; entry.y = edge-id | (own&127)<<22
__global__ __launch_bounds__(256) void passB_kernel(
    const int* __restrict__ ei, int* __restrict__ bcur, uint2* __restrict__ tmp,
    int E, int M, int NB)
{
    __shared__ int hist[NB_MAX];
    __shared__ int lbase[NB_MAX];
    __shared__ int gpos[NB_MAX];
    __shared__ int aux[256];
    __shared__ uint2 stage[CHUNKB];
    int tid = threadIdx.x;
    int start = blockIdx.x * CHUNKB;
    if (start >= M) return;
    int cnt = M - start; if (cnt > CHUNKB) cnt = CHUNKB;
    for (int i = tid; i < NB_MAX; i += 256) hist[i] = 0;
    __syncthreads();
    for (int i = tid; i < cnt; i += 256) {
        int de = start + i;
        int own = ei[de < E ? de + E : de - E];
        atomicAdd(&hist[own >> SHIFT], 1);
    }
    __syncthreads();
    {   // exclusive scan hist[0..1023] -> lbase, 256 threads x 4 items
        int t4 = tid * 4;
        int a0 = hist[t4], a1 = hist[t4+1], a2 = hist[t4+2], a3 = hist[t4+3];
        aux[tid] = a0 + a1 + a2 + a3;
        __syncthreads();
        for (int off = 1; off < 256; off <<= 1) {
            int v = (tid >= off) ? aux[tid - off] : 0;
            __syncthreads();
            aux[tid] += v;
            __syncthreads();
        }
        int te = (tid == 0) ? 0 : aux[tid - 1];
        lbase[t4]   = te;
        lbase[t4+1] = te + a0;
        lbase[t4+2] = te + a0 + a1;
        lbase[t4+3] = te + a0 + a1 + a2;
    }
    __syncthreads();
    for (int b = tid; b < NB; b += 256) {
        int cb = hist[b];
        gpos[b] = cb ? atomicAdd(&bcur[b], cb) : 0;
    }
    __syncthreads();
    for (int i = tid; i < NB_MAX; i += 256) hist[i] = 0;  // reuse as cursor
    __syncthreads();
    for (int i = tid; i < cnt; i += 256) {
        int de = start + i;
        int j = de < E ? de : de - E;
        int own = ei[de < E ? de + E : de - E];
        unsigned nbr = (unsigned)ei[de];
        int b = own >> SHIFT;
        int p = atomicAdd(&hist[b], 1);
        stage[lbase[b] + p] = make_uint2(nbr, (unsigned)j | ((unsigned)(own & 127) << 22));
    }
    __syncthreads();
    int wave = tid >> 6, lane = tid & 63;
    for (int b = wave; b < NB; b += 4) {
        int n_b = hist[b];
        if (!n_b) continue;
        int lo = lbase[b], g = gpos[b];
        int lim = (b + 1) * BCAP;          // capacity guard (statistically never hit)
        for (int k = lane; k < n_b; k += 64) {
            if (g + k < lim) tmp[(size_t)g + k] = stage[lo + k];
        }
    }
}

// ---------------- K4: per-bucket node sort in place -> (off, deg) ---------------
__global__ __launch_bounds__(256) void passC_kernel(
    uint2* __restrict__ tmp, const int* __restrict__ bcur,
    int* __restrict__ off, int* __restrict__ deg, int N)
{
    __shared__ uint2 ordered[BCAP];
    __shared__ int hist[128], nexcl[128], cur[128], s2[128];
    int tid = threadIdx.x;
    int b = blockIdx.x;
    int lo = b * BCAP;
    int cnt = bcur[b] - lo;
    if (cnt > BCAP) cnt = BCAP;
    if (tid < 128) hist[tid] = 0;
    __syncthreads();
    for (int i = tid; i < cnt; i += 256)
        atomicAdd(&hist[(tmp[(size_t)lo + i].y >> 22) & 127], 1);
    __syncthreads();
    if (tid < 128) s2[tid] = hist[tid];
    __syncthreads();
    for (int o = 1; o < 128; o <<= 1) {
        int v = (tid < 128 && tid >= o) ? s2[tid - o] : 0;
        __syncthreads();
        if (tid < 128) s2[tid] += v;
        __syncthreads();
    }
    if (tid < 128) {
        int excl = s2[tid] - hist[tid];
        nexcl[tid] = excl;
        cur[tid] = 0;
        int node = (b << SHIFT) + tid;
        if (node < N) { off[node] = lo + excl; deg[node] = hist[tid]; }
    }
    __syncthreads();
    for (int i = tid; i < cnt; i += 256) {
        uint2 en = tmp[(size_t)lo + i];
        int ol = (en.y >> 22) & 127;
        int p = atomicAdd(&cur[ol], 1);
        ordered[nexcl[ol] + p] = en;
    }
    __syncthreads();
    for (int i = tid; i < cnt; i += 256) tmp[(size_t)lo + i] = ordered[i];
}

// ---------------- K5: h1 = x@root1+bias1 ; x_h = fp16(x) ------------------------
__global__ __launch_bounds__(256) void node_prep1b(
    const float* __restrict__ x, const float* __restrict__ root1,
    const float* __restrict__ bias1, float* __restrict__ h1,
    __half* __restrict__ x_h, int N)
{
    __shared__ float r1s[64 * 21];
    __shared__ float sb[20];
    int tid = threadIdx.x;
    for (int i = tid; i < 1280; i += 256) {
        int f = i / 20, h = i % 20;
        r1s[f*21 + h] = root1[i];
    }
    if (tid < 20) sb[tid] = bias1[tid];
    __syncthreads();
    int t = blockIdx.x * 256 + tid;
    int n = t >> 3, q = t & 7;
    if (n >= N) return;
    const float4* xr = (const float4*)(x + (size_t)n*64 + q*8);
    float4 va = xr[0], vb = xr[1];
    float xf[8] = {va.x, va.y, va.z, va.w, vb.x, vb.y, vb.z, vb.w};
    __half hh[8];
    #pragma unroll
    for (int j = 0; j < 8; ++j) hh[j] = __float2half(xf[j]);
    *(uint4*)(x_h + (size_t)n*64 + q*8) = *(const uint4*)hh;
    float p[20];
    #pragma unroll
    for (int h = 0; h < 20; ++h) p[h] = 0.f;
    #pragma unroll
    for (int j = 0; j < 8; ++j) {
        float xv = xf[j];
        int base = (q*8 + j) * 21;
        #pragma unroll
        for (int h = 0; h < 20; ++h) p[h] += xv * r1s[base + h];
    }
    #pragma unroll
    for (int m = 1; m < 8; m <<= 1) {
        #pragma unroll
        for (int h = 0; h < 20; ++h) p[h] += __shfl_xor(p[h], m, 64);
    }
    if (q < 5) {
        float4 o;
        o.x = p[q*4+0] + sb[q*4+0];
        o.y = p[q*4+1] + sb[q*4+1];
        o.z = p[q*4+2] + sb[q*4+2];
        o.w = p[q*4+3] + sb[q*4+3];
        *(float4*)(h1 + (size_t)n*20 + q*4) = o;
    }
}

// ---------------- K6: gather layer 1 (4-edge ILP) + theta1 + fused node_prep2 ---
__global__ __launch_bounds__(256) void gather1_fused(
    const int* __restrict__ off, const int* __restrict__ deg,
    const uint2* __restrict__ fin, const float4* __restrict__ wedge1,
    const __half* __restrict__ x_h, const float* __restrict__ h1,
    const float* __restrict__ theta1,
    const float* __restrict__ root2, const float* __restrict__ theta2,
    const float* __restrict__ bias2,
    float* __restrict__ o2, float* __restrict__ P2, int N)
{
    __shared__ float th[4 * 64 * 21];
    __shared__ float w2s[200];
    __shared__ float w2b[2];
    int tid = threadIdx.x;
    for (int i = tid; i < 5120; i += 256) {
        int l = i / 1280, f = (i / 20) % 64, h = i % 20;
        th[(l*64 + f)*21 + h] = theta1[i];
    }
    for (int i = tid; i < 200; i += 256) {
        int o = i / 20, h = i % 20;
        float v;
        if (o < 2) v = root2[h*2 + o];
        else { int l = (o-2) >> 1, jj = (o-2) & 1; v = theta2[l*40 + h*2 + jj]; }
        w2s[i] = v;
    }
    if (tid < 2) w2b[tid] = bias2[tid];
    __syncthreads();
    int t = blockIdx.x * 256 + tid;
    int n = t >> 3, q = t & 7;
    if (n >= N) return;
    int start = off[n];
    int c = deg[n];
    const uint2* sl = fin + start;
    float acc[4][8];
    #pragma unroll
    for (int l = 0; l < 4; ++l)
        #pragma unroll
        for (int j = 0; j < 8; ++j) acc[l][j] = 0.f;
    int q4 = (c + 3) >> 2;
    for (int i = 0; i < q4; ++i) {
        int id[4];
        uint2 en[4];
        float4 w[4];
        uint4 hx[4];
        #pragma unroll
        for (int k = 0; k < 4; ++k) {
            id[k] = i + k * q4;
            int idc = id[k] < c ? id[k] : 0;
            en[k] = sl[idc];
        }
        #pragma unroll
        for (int k = 0; k < 4; ++k) {
            w[k] = wedge1[en[k].y & 0x3FFFFFu];
            hx[k] = *(const uint4*)(x_h + (size_t)(int)en[k].x * 64 + q * 8);
        }
        #pragma unroll
        for (int k = 0; k < 4; ++k) {
            float z = (id[k] < c) ? 1.f : 0.f;
            w[k].x *= z; w[k].y *= z; w[k].z *= z; w[k].w *= z;
        }
        #pragma unroll
        for (int k = 0; k < 4; ++k) {
            const __half* hp = (const __half*)&hx[k];
            #pragma unroll
            for (int j2 = 0; j2 < 8; ++j2) {
                float xv = __half2float(hp[j2]);
                acc[0][j2] += w[k].x * xv;
                acc[1][j2] += w[k].y * xv;
                acc[2][j2] += w[k].z * xv;
                acc[3][j2] += w[k].w * xv;
            }
        }
    }
    float p[20];
    #pragma unroll
    for (int h = 0; h < 20; ++h) p[h] = 0.f;
    #pragma unroll
    for (int l = 0; l < 4; ++l) {
        #pragma unroll
        for (int j2 = 0; j2 < 8; ++j2) {
            float a = acc[l][j2];
            int base = ((l << 6) + (q << 3) + j2) * 21;
            #pragma unroll
            for (int h = 0; h < 20; ++h) p[h] += a * th[base + h];
        }
    }
    #pragma unroll
    for (int m = 1; m < 8; m <<= 1) {
        #pragma unroll
        for (int h = 0; h < 20; ++h) p[h] += __shfl_xor(p[h], m, 64);
    }
    const float4* hb = (const float4*)(h1 + (size_t)n*20);
    float hv[20];
    #pragma unroll
    for (int qq = 0; qq < 5; ++qq) {
        float4 v = hb[qq];
        hv[qq*4+0] = fmaxf(p[qq*4+0] + v.x, 0.f);
        hv[qq*4+1] = fmaxf(p[qq*4+1] + v.y, 0.f);
        hv[qq*4+2] = fmaxf(p[qq*4+2] + v.z, 0.f);
        hv[qq*4+3] = fmaxf(p[qq*4+3] + v.w, 0.f);
    }
    for (int o = q; o < 10; o += 8) {
        float v = (o < 2) ? w2b[o] : 0.f;
        #pragma unroll
        for (int h = 0; h < 20; ++h) v += hv[h] * w2s[o*20 + h];
        if (o < 2) o2[(size_t)n*2 + o] = v;
        else       P2[(size_t)n*8 + (o - 2)] = v;
    }
}

// ---------------- K7: gather layer 2 (8 lanes/node) + log_softmax ---------------
__global__ __launch_bounds__(256) void gather2_lsm_kernel(
    const int* __restrict__ off, const int* __restrict__ deg,
    const uint2* __restrict__ fin, const float4* __restrict__ wedge2,
    const float4* __restrict__ P2, const float* __restrict__ o2,
    float* __restrict__ out, int N)
{
    int t = blockIdx.x * 256 + threadIdx.x;
    int n = t >> 3, r = t & 7;
    if (n >= N) return;
    int start = off[n];
    int c = deg[n];
    const uint2* sl = fin + start;
    float o0 = 0.f, o1 = 0.f;
    for (int i = r; i < c; i += 8) {
        uint2 en = sl[i];
        int nbr = (int)en.x;
        unsigned we = en.y & 0x3FFFFFu;
        float4 w = wedge2[we];
        float4 pa = P2[(size_t)nbr*2], pb = P2[(size_t)nbr*2 + 1];
        o0 += w.x*pa.x + w.y*pa.z + w.z*pb.x + w.w*pb.z;
        o1 += w.x*pa.y + w.y*pa.w + w.z*pb.y + w.w*pb.w;
    }
    #pragma unroll
    for (int m = 1; m < 8; m <<= 1) {
        o0 += __shfl_xor(o0, m, 64);
        o1 += __shfl_xor(o1, m, 64);
    }
    if (r == 0) {
        o0 += o2[(size_t)n*2];
        o1 += o2[(size_t)n*2 + 1];
        float mx = fmaxf(o0, o1);
        float lse = mx + logf(expf(o0 - mx) + expf(o1 - mx));
        out[(size_t)n*2]     = o0 - lse;
        out[(size_t)n*2 + 1] = o1 - lse;
    }
}

// ================= Fallback path (atomic scatter, R1-style) =====================
__global__ __launch_bounds__(256) void node_prep1(
    const float* __restrict__ x, const float* __restrict__ root1,
    const float* __restrict__ theta1, const float* __restrict__ bias1,
    float* __restrict__ h1, float* __restrict__ P1, int N)
{
    __shared__ float Ws[64 * 100];
    __shared__ float xs[8 * 64];
    __shared__ float sb[20];
    int tid = threadIdx.x;
    for (int i = tid; i < 6400; i += 256) {
        int f = i / 100, c = i % 100;
        float v;
        if (c < 20) v = root1[f*20 + c];
        else { int l = (c-20)/20, hh = (c-20)%20; v = theta1[l*1280 + f*20 + hh]; }
        Ws[i] = v;
    }
    if (tid < 20) sb[tid] = bias1[tid];
    int nb = blockIdx.x * 8;
    for (int i = tid; i < 512; i += 256) {
        int nl = i >> 6, f = i & 63;
        int n = nb + nl;
        xs[i] = (n < N) ? x[(size_t)n*64 + f] : 0.f;
    }
    __syncthreads();
    for (int i = tid; i < 800; i += 256) {
        int nl = i / 100, c = i % 100;
        int n = nb + nl;
        if (n >= N) continue;
        float acc = 0.f;
        #pragma unroll 16
        for (int f = 0; f < 64; ++f) acc += xs[nl*64 + f] * Ws[f*100 + c];
        if (c < 20) h1[(size_t)n*20 + c] = acc + sb[c];
        else        P1[(size_t)n*80 + (c - 20)] = acc;
    }
}

__global__ __launch_bounds__(256) void edge_scatter1(
    const int* __restrict__ ei, const float4* __restrict__ wedge1,
    const float4* __restrict__ P1, float* __restrict__ h1, int E)
{
    int e = blockIdx.x * 256 + threadIdx.x;
    if (e >= E) return;
    int s = ei[e], d = ei[E + e];
    float4 w = wedge1[e];
    const float4* Ps = P1 + (size_t)s * 20;
    const float4* Pd = P1 + (size_t)d * 20;
    float* Hs = h1 + (size_t)s * 20;
    float* Hd = h1 + (size_t)d * 20;
    #pragma unroll
    for (int q = 0; q < 5; ++q) {
        float4 a0 = Ps[q], a1 = Ps[5+q], a2 = Ps[10+q], a3 = Ps[15+q];
        atomicAdd(Hd + q*4 + 0, w.x*a0.x + w.y*a1.x + w.z*a2.x + w.w*a3.x);
        atomicAdd(Hd + q*4 + 1, w.x*a0.y + w.y*a1.y + w.z*a2.y + w.w*a3.y);
        atomicAdd(Hd + q*4 + 2, w.x*a0.z + w.y*a1.z + w.z*a2.z + w.w*a3.z);
        atomicAdd(Hd + q*4 + 3, w.x*a0.w + w.y*a1.w + w.z*a2.w + w.w*a3.w);
        float4 b0 = Pd[q], b1 = Pd[5+q], b2 = Pd[10+q], b3 = Pd[15+q];
        atomicAdd(Hs + q*4 + 0, w.x*b0.x + w.y*b1.x + w.z*b2.x + w.w*b3.x);
        atomicAdd(Hs + q*4 + 1, w.x*b0.y + w.y*b1.y + w.z*b2.y + w.w*b3.y);
        atomicAdd(Hs + q*4 + 2, w.x*b0.z + w.y*b1.z + w.z*b2.z + w.w*b3.z);
        atomicAdd(Hs + q*4 + 3, w.x*b0.w + w.y*b1.w + w.z*b2.w + w.w*b3.w);
    }
}

__global__ __launch_bounds__(256) void node_prep2(
    const float* __restrict__ h1, const float* __restrict__ root2,
    const float* __restrict__ theta2, const float* __restrict__ bias2,
    float* __restrict__ out2, float* __restrict__ P2, int N)
{
    __shared__ float sr[40], st[160], sb2[2];
    int tid = threadIdx.x;
    if (tid < 40) sr[tid] = root2[tid];
    if (tid >= 64 && tid < 224) st[tid - 64] = theta2[tid - 64];
    if (tid < 2) sb2[tid] = bias2[tid];
    __syncthreads();
    int n = blockIdx.x * 256 + tid;
    if (n >= N) return;
    float hv[20];
    const float4* hp = (const float4*)(h1 + (size_t)n * 20);
    #pragma unroll
    for (int q = 0; q < 5; ++q) {
        float4 v = hp[q];
        hv[q*4+0] = fmaxf(v.x, 0.f);
        hv[q*4+1] = fmaxf(v.y, 0.f);
        hv[q*4+2] = fmaxf(v.z, 0.f);
        hv[q*4+3] = fmaxf(v.w, 0.f);
    }
    float o0 = sb2[0], o1 = sb2[1];
    #pragma unroll
    for (int h = 0; h < 20; ++h) { o0 += hv[h]*sr[h*2]; o1 += hv[h]*sr[h*2+1]; }
    out2[(size_t)n*2 + 0] = o0;
    out2[(size_t)n*2 + 1] = o1;
    #pragma unroll
    for (int l = 0; l < 4; ++l) {
        float p0 = 0.f, p1 = 0.f;
        #pragma unroll
        for (int h = 0; h < 20; ++h) {
            p0 += hv[h]*st[l*40 + h*2];
            p1 += hv[h]*st[l*40 + h*2 + 1];
        }
        P2[(size_t)n*8 + l*2 + 0] = p0;
        P2[(size_t)n*8 + l*2 + 1] = p1;
    }
}

__global__ __launch_bounds__(256) void edge_scatter2(
    const int* __restrict__ ei, const float4* __restrict__ wedge2,
    const float4* __restrict__ P2, float* __restrict__ out2, int E)
{
    int e = blockIdx.x * 256 + threadIdx.x;
    if (e >= E) return;
    int s = ei[e], d = ei[E + e];
    float4 w = wedge2[e];
    float4 pa = P2[(size_t)s*2], pb = P2[(size_t)s*2 + 1];
    float y0 = w.x*pa.x + w.y*pa.z + w.z*pb.x + w.w*pb.z;
    float y1 = w.x*pa.y + w.y*pa.w + w.z*pb.y + w.w*pb.w;
    atomicAdd(out2 + (size_t)d*2 + 0, y0);
    atomicAdd(out2 + (size_t)d*2 + 1, y1);
    float4 qa = P2[(size_t)d*2], qb = P2[(size_t)d*2 + 1];
    float z0 = w.x*qa.x + w.y*qa.z + w.z*qb.x + w.w*qb.z;
    float z1 = w.x*qa.y + w.y*qa.w + w.z*qb.y + w.w*qb.w;
    atomicAdd(out2 + (size_t)s*2 + 0, z0);
    atomicAdd(out2 + (size_t)s*2 + 1, z1);
}

__global__ __launch_bounds__(256) void logsoftmax_k(
    const float* __restrict__ out2, float* __restrict__ out, int N)
{
    int n = blockIdx.x * 256 + threadIdx.x;
    if (n >= N) return;
    float o0 = out2[(size_t)n*2], o1 = out2[(size_t)n*2 + 1];
    float m = fmaxf(o0, o1);
    float lse = m + logf(expf(o0 - m) + expf(o1 - m));
    out[(size_t)n*2]     = o0 - lse;
    out[(size_t)n*2 + 1] = o1 - lse;
}

extern "C" void kernel_launch(void* const* d_in, const int* in_sizes, int n_in,
                              void* d_out, int out_size, void* d_ws, size_t ws_size,
                              hipStream_t stream)
{
    const float* x     = (const float*)d_in[0];
    const int*   ei    = (const int*)d_in[1];
    const float* attr  = (const float*)d_in[2];
    const float* cut   = (const float*)d_in[3];
    const float* cw1   = (const float*)d_in[4];
    const float* cb1   = (const float*)d_in[5];
    const float* f1w1  = (const float*)d_in[6];
    const float* f1b1  = (const float*)d_in[7];
    const float* f2w1  = (const float*)d_in[8];
    const float* f2b1  = (const float*)d_in[9];
    const float* th1   = (const float*)d_in[10];
    const float* rt1   = (const float*)d_in[11];
    const float* bs1   = (const float*)d_in[12];
    const float* cw2   = (const float*)d_in[13];
    const float* cb2   = (const float*)d_in[14];
    const float* f1w2  = (const float*)d_in[15];
    const float* f1b2  = (const float*)d_in[16];
    const float* f2w2  = (const float*)d_in[17];
    const float* f2b2  = (const float*)d_in[18];
    const float* th2   = (const float*)d_in[19];
    const float* rt2   = (const float*)d_in[20];
    const float* bs2   = (const float*)d_in[21];

    const int N = in_sizes[0] / 64;
    const int E = in_sizes[1] / 2;
    const int M = 2 * E;
    const int NB = (N + 127) >> SHIFT;
    const int Eh = (E + 1) >> 1;

    // ---- workspace layout (words) ----
    size_t W = 0;
    float* ws = (float*)d_ws;
    float* wedge1 = ws + W;            W += (size_t)E * 4;
    float* wedge2 = ws + W;            W += (size_t)E * 4;
    uint2* tmp    = (uint2*)(ws + W);  W += (size_t)NB * BCAP * 2;  // padded buckets
    int* off      = (int*)(ws + W);    W += N;
    int* deg      = (int*)(ws + W);    W += N;
    int* bcur     = (int*)(ws + W);    W += NB;
    W = (W + 31) & ~(size_t)31;
    __half* x_h = (__half*)(ws + W);               // 32N words
    float*  h1  = ws + W + (size_t)N * 32;         // 20N
    float*  P2  = ws + W + (size_t)N * 52;         // 8N
    float*  o2  = ws + W + (size_t)N * 60;         // 2N
    size_t need_new = W + (size_t)N * 62;

    bool okNew = (NB <= NB_MAX) && (E <= 0x3FFFFF) && (ws_size / 4 >= need_new);

    if (okNew) {
        filter_kernel<<<(Eh + 255) / 256, 256, 0, stream>>>(
            attr, cut, cw1, cb1, f1w1, f1b1, f2w1, f2b1,
            cw2, cb2, f1w2, f1b2, f2w2, f2b2, wedge1, wedge2, E);
        init_bcur_kernel<<<(NB + 255) / 256, 256, 0, stream>>>(bcur, NB);
        passB_kernel<<<(M + CHUNKB - 1) / CHUNKB, 256, 0, stream>>>(
            ei, bcur, tmp, E, M, NB);
        passC_kernel<<<NB, 256, 0, stream>>>(tmp, bcur, off, deg, N);
        node_prep1b<<<(N * 8 + 255) / 256, 256, 0, stream>>>(x, rt1, bs1, h1, x_h, N);
        gather1_fused<<<(N * 8 + 255) / 256, 256, 0, stream>>>(
            off, deg, tmp, (const float4*)wedge1, x_h, h1,
            th1, rt2, th2, bs2, o2, P2, N);
        gather2_lsm_kernel<<<(N * 8 + 255) / 256, 256, 0, stream>>>(
            off, deg, tmp, (const float4*)wedge2, (const float4*)P2, o2,
            (float*)d_out, N);
    } else {
        // Fallback: atomic scatter (correct but slow). Independent layout.
        float* fw1 = ws;                           // 4E
        float* fw2 = fw1 + (size_t)E * 4;          // 4E
        float* P1  = fw2 + (size_t)E * 4;          // 80N
        float* fh1 = P1  + (size_t)N * 80;         // 20N
        float* fP2 = fh1 + (size_t)N * 20;         // 8N
        float* fo2 = fP2 + (size_t)N * 8;          // 2N
        filter_kernel<<<(Eh + 255) / 256, 256, 0, stream>>>(
            attr, cut, cw1, cb1, f1w1, f1b1, f2w1, f2b1,
            cw2, cb2, f1w2, f1b2, f2w2, f2b2, fw1, fw2, E);
        node_prep1<<<(N + 7) / 8, 256, 0, stream>>>(x, rt1, th1, bs1, fh1, P1, N);
        edge_scatter1<<<(E + 255) / 256, 256, 0, stream>>>(
            ei, (const float4*)fw1, (const float4*)P1, fh1, E);
        node_prep2<<<(N + 255) / 256, 256, 0, stream>>>(fh1, rt2, th2, bs2, fo2, fP2, N);
        edge_scatter2<<<(E + 255) / 256, 256, 0, stream>>>(
            ei, (const float4*)fw2, (const float4*)fP2, fo2, E);
        logsoftmax_k<<<(N + 255) / 256, 256, 0, stream>>>(fo2, (float*)d_out, N);
    }
}

// Round 8
// 613.289 us; speedup vs baseline: 1.1113x; 1.1113x over previous
//
#include <hip/hip_runtime.h>
#include <hip/hip_fp16.h>
#include <math.h>

// Problem constants: F_IN=64, K=16, C=20, L=4, H1=20, H2=2
// N=100k nodes, E=1.6M undirected edges, M=2E=3.2M directed entries.
//
// R7 lesson: gather1 is NOT per-thread-MLP limited (4-edge ILP = no change,
// ~2.4 TB/s effective random-line ceiling) and 2-edge filter regressed via
// VGPR pressure. This round: revert both to R6 forms; fold bcur init into
// filter; store P2 in fp16 (halves gather2's random row + L2 footprint).

#define SHIFT   7
#define NB_MAX  1024
#define CHUNKB  6144
#define BCAP    4608

// ---------------- K1: filter nets (analytic conv), one edge per thread ----------
// Also initializes bcur (bucket cursors) to capacity bases — saves a launch.
__global__ __launch_bounds__(256) void filter_kernel(
    const float* __restrict__ attr, const float* __restrict__ cutoffs,
    const float* __restrict__ cw1, const float* __restrict__ cb1,
    const float* __restrict__ f1w1, const float* __restrict__ f1b1,
    const float* __restrict__ f2w1, const float* __restrict__ f2b1,
    const float* __restrict__ cw2, const float* __restrict__ cb2,
    const float* __restrict__ f1w2, const float* __restrict__ f1b2,
    const float* __restrict__ f2w2, const float* __restrict__ f2b2,
    float* __restrict__ wedge1, float* __restrict__ wedge2,
    int* __restrict__ bcur, int NB, int E)
{
    __shared__ float s_cut[16];
    __shared__ float s_w[2][344]; // cw(120) cb(20) f1w(160) f1b(8) f2w(32) f2b(4)
    __shared__ float tab[2 * 20 * 64];
    int tid = threadIdx.x;
    int gb = blockIdx.x * 256 + tid;
    if (gb < NB) bcur[gb] = gb * BCAP;
    if (tid < 16) s_cut[tid] = cutoffs[tid];
    for (int i = tid; i < 344; i += 256) {
        float v1, v2;
        if (i < 120)      { v1 = cw1[i];       v2 = cw2[i]; }
        else if (i < 140) { v1 = cb1[i-120];   v2 = cb2[i-120]; }
        else if (i < 300) { v1 = f1w1[i-140];  v2 = f1w2[i-140]; }
        else if (i < 308) { v1 = f1b1[i-300];  v2 = f1b2[i-300]; }
        else if (i < 340) { v1 = f2w1[i-308];  v2 = f2w2[i-308]; }
        else              { v1 = f2b1[i-340];  v2 = f2b2[i-340]; }
        s_w[0][i] = v1; s_w[1][i] = v2;
    }
    __syncthreads();
    if (tid < 40) {
        int l = tid / 20, ch = tid % 20;
        const float* W = s_w[l];
        float w00 = W[ch*6+0], w01 = W[ch*6+1], w02 = W[ch*6+2];
        float w10 = W[ch*6+3], w11 = W[ch*6+4], w12 = W[ch*6+5];
        float b = W[120 + ch];
        float* tb = &tab[(l*20 + ch) * 64];
        tb[0]  = w01*s_cut[0]  + w02*s_cut[1];
        for (int k = 1; k <= 14; ++k)
            tb[k] = w00*s_cut[k-1] + w01*s_cut[k] + w02*s_cut[k+1];
        tb[15] = w00*s_cut[14] + w01*s_cut[15];
        float pm = tb[1]; tb[16+1] = pm;
        for (int j = 2; j <= 14; ++j) { pm = fminf(pm, tb[j]); tb[16+j] = pm; }
        float qm = tb[14]; tb[32+14] = qm;
        for (int j = 13; j >= 1; --j) { qm = fminf(qm, tb[j]); tb[32+j] = qm; }
        tb[48] = w00 + w01 + w02;
        tb[49] = w01 + w02;
        tb[50] = w00 + w01;
        tb[51] = w10 + w11 + w12;
        tb[52] = w10 + w11;
        tb[53] = w10;
        tb[54] = w11;
        tb[55] = w12;
        tb[56] = b;
    }
    __syncthreads();
    int e = gb;
    if (e >= E) return;

    float a = attr[e];
    int idx = 0;
    #pragma unroll
    for (int k = 0; k < 16; ++k) idx += (a > s_cut[k]) ? 1 : 0;

    #pragma unroll
    for (int layer = 0; layer < 2; ++layer) {
        const float* W = s_w[layer];
        float h[20];
        #pragma unroll
        for (int c = 0; c < 20; ++c) {
            const float* tb = &tab[(layer*20 + c) * 64];
            float b = tb[56];
            float base = fmaf(tb[48], a, b);
            float y0 = fmaf(tb[49], a, b) - tb[0];
            y0 += (idx >= 1 ? tb[54] : 0.f) + (idx >= 2 ? tb[55] : 0.f);
            float m = y0;
            float y15 = fmaf(tb[50], a, b) - tb[15];
            y15 += (idx >= 15 ? tb[53] : 0.f) + (idx >= 16 ? tb[54] : 0.f);
            m = fmaxf(m, y15);
            {
                int j = idx - 2; j = j > 14 ? 14 : j;
                float v = base + tb[51] - tb[16 + j];
                m = (idx >= 3) ? fmaxf(m, v) : m;
            }
            {
                float v = base + tb[52] - tb[(idx >= 2 && idx <= 15) ? (idx-1) : 1];
                m = (idx >= 2 && idx <= 15) ? fmaxf(m, v) : m;
            }
            {
                float v = base + tb[53] - tb[(idx >= 1 && idx <= 14) ? idx : 1];
                m = (idx >= 1 && idx <= 14) ? fmaxf(m, v) : m;
            }
            {
                int j = idx + 1; j = j < 1 ? 1 : j;
                float v = base - tb[32 + (j > 14 ? 14 : j)];
                m = (idx <= 13) ? fmaxf(m, v) : m;
            }
            h[c] = fmaxf(m, 0.f);
        }
        float g[8];
        #pragma unroll
        for (int j = 0; j < 8; ++j) {
            float t = W[300 + j];
            #pragma unroll
            for (int c = 0; c < 20; ++c) t += W[140 + j*20 + c] * h[c];
            g[j] = fmaxf(t, 0.f);
        }
        float4 wo;
        float* wp = (float*)&wo;
        #pragma unroll
        for (int l = 0; l < 4; ++l) {
            float t = W[340 + l];
            #pragma unroll
            for (int j = 0; j < 8; ++j) t += W[308 + l*8 + j] * g[j];
            wp[l] = fmaxf(t, 0.f);
        }
        float4* dstp = (float4*)(layer == 0 ? wedge1 : wedge2);
        dstp[e] = wo;
    }
}

// ---------------- K3: scatter directed entries into capacity buckets ------------
// entry.x = nbr node; entry.y = edge-id | (own&127)<<22
__global__ __launch_bounds__(256) void passB_kernel(
    const int* __restrict__ ei, int* __restrict__ bcur, uint2* __restrict__ tmp,
    int E, int M, int NB)
{
    __shared__ int hist[NB_MAX];
    __shared__ int lbase[NB_MAX];
    __shared__ int gpos[NB_MAX];
    __shared__ int aux[256];
    __shared__ uint2 stage[CHUNKB];
    int tid = threadIdx.x;
    int start = blockIdx.x * CHUNKB;
    if (start >= M) return;
    int cnt = M - start; if (cnt > CHUNKB) cnt = CHUNKB;
    for (int i = tid; i < NB_MAX; i += 256) hist[i] = 0;
    __syncthreads();
    for (int i = tid; i < cnt; i += 256) {
        int de = start + i;
        int own = ei[de < E ? de + E : de - E];
        atomicAdd(&hist[own >> SHIFT], 1);
    }
    __syncthreads();
    {   // exclusive scan hist[0..1023] -> lbase, 256 threads x 4 items
        int t4 = tid * 4;
        int a0 = hist[t4], a1 = hist[t4+1], a2 = hist[t4+2], a3 = hist[t4+3];
        aux[tid] = a0 + a1 + a2 + a3;
        __syncthreads();
        for (int off = 1; off < 256; off <<= 1) {
            int v = (tid >= off) ? aux[tid - off] : 0;
            __syncthreads();
            aux[tid] += v;
            __syncthreads();
        }
        int te = (tid == 0) ? 0 : aux[tid - 1];
        lbase[t4]   = te;
        lbase[t4+1] = te + a0;
        lbase[t4+2] = te + a0 + a1;
        lbase[t4+3] = te + a0 + a1 + a2;
    }
    __syncthreads();
    for (int b = tid; b < NB; b += 256) {
        int cb = hist[b];
        gpos[b] = cb ? atomicAdd(&bcur[b], cb) : 0;
    }
    __syncthreads();
    for (int i = tid; i < NB_MAX; i += 256) hist[i] = 0;  // reuse as cursor
    __syncthreads();
    for (int i = tid; i < cnt; i += 256) {
        int de = start + i;
        int j = de < E ? de : de - E;
        int own = ei[de < E ? de + E : de - E];
        unsigned nbr = (unsigned)ei[de];
        int b = own >> SHIFT;
        int p = atomicAdd(&hist[b], 1);
        stage[lbase[b] + p] = make_uint2(nbr, (unsigned)j | ((unsigned)(own & 127) << 22));
    }
    __syncthreads();
    int wave = tid >> 6, lane = tid & 63;
    for (int b = wave; b < NB; b += 4) {
        int n_b = hist[b];
        if (!n_b) continue;
        int lo = lbase[b], g = gpos[b];
        int lim = (b + 1) * BCAP;          // capacity guard (statistically never hit)
        for (int k = lane; k < n_b; k += 64) {
            if (g + k < lim) tmp[(size_t)g + k] = stage[lo + k];
        }
    }
}

// ---------------- K4: per-bucket node sort in place -> (off, deg) ---------------
__global__ __launch_bounds__(256) void passC_kernel(
    uint2* __restrict__ tmp, const int* __restrict__ bcur,
    int* __restrict__ off, int* __restrict__ deg, int N)
{
    __shared__ uint2 ordered[BCAP];
    __shared__ int hist[128], nexcl[128], cur[128], s2[128];
    int tid = threadIdx.x;
    int b = blockIdx.x;
    int lo = b * BCAP;
    int cnt = bcur[b] - lo;
    if (cnt > BCAP) cnt = BCAP;
    if (tid < 128) hist[tid] = 0;
    __syncthreads();
    for (int i = tid; i < cnt; i += 256)
        atomicAdd(&hist[(tmp[(size_t)lo + i].y >> 22) & 127], 1);
    __syncthreads();
    if (tid < 128) s2[tid] = hist[tid];
    __syncthreads();
    for (int o = 1; o < 128; o <<= 1) {
        int v = (tid < 128 && tid >= o) ? s2[tid - o] : 0;
        __syncthreads();
        if (tid < 128) s2[tid] += v;
        __syncthreads();
    }
    if (tid < 128) {
        int excl = s2[tid] - hist[tid];
        nexcl[tid] = excl;
        cur[tid] = 0;
        int node = (b << SHIFT) + tid;
        if (node < N) { off[node] = lo + excl; deg[node] = hist[tid]; }
    }
    __syncthreads();
    for (int i = tid; i < cnt; i += 256) {
        uint2 en = tmp[(size_t)lo + i];
        int ol = (en.y >> 22) & 127;
        int p = atomicAdd(&cur[ol], 1);
        ordered[nexcl[ol] + p] = en;
    }
    __syncthreads();
    for (int i = tid; i < cnt; i += 256) tmp[(size_t)lo + i] = ordered[i];
}

// ---------------- K5: h1 = x@root1+bias1 ; x_h = fp16(x) ------------------------
__global__ __launch_bounds__(256) void node_prep1b(
    const float* __restrict__ x, const float* __restrict__ root1,
    const float* __restrict__ bias1, float* __restrict__ h1,
    __half* __restrict__ x_h, int N)
{
    __shared__ float r1s[64 * 21];
    __shared__ float sb[20];
    int tid = threadIdx.x;
    for (int i = tid; i < 1280; i += 256) {
        int f = i / 20, h = i % 20;
        r1s[f*21 + h] = root1[i];
    }
    if (tid < 20) sb[tid] = bias1[tid];
    __syncthreads();
    int t = blockIdx.x * 256 + tid;
    int n = t >> 3, q = t & 7;
    if (n >= N) return;
    const float4* xr = (const float4*)(x + (size_t)n*64 + q*8);
    float4 va = xr[0], vb = xr[1];
    float xf[8] = {va.x, va.y, va.z, va.w, vb.x, vb.y, vb.z, vb.w};
    __half hh[8];
    #pragma unroll
    for (int j = 0; j < 8; ++j) hh[j] = __float2half(xf[j]);
    *(uint4*)(x_h + (size_t)n*64 + q*8) = *(const uint4*)hh;
    float p[20];
    #pragma unroll
    for (int h = 0; h < 20; ++h) p[h] = 0.f;
    #pragma unroll
    for (int j = 0; j < 8; ++j) {
        float xv = xf[j];
        int base = (q*8 + j) * 21;
        #pragma unroll
        for (int h = 0; h < 20; ++h) p[h] += xv * r1s[base + h];
    }
    #pragma unroll
    for (int m = 1; m < 8; m <<= 1) {
        #pragma unroll
        for (int h = 0; h < 20; ++h) p[h] += __shfl_xor(p[h], m, 64);
    }
    if (q < 5) {
        float4 o;
        o.x = p[q*4+0] + sb[q*4+0];
        o.y = p[q*4+1] + sb[q*4+1];
        o.z = p[q*4+2] + sb[q*4+2];
        o.w = p[q*4+3] + sb[q*4+3];
        *(float4*)(h1 + (size_t)n*20 + q*4) = o;
    }
}

// ---------------- K6: gather layer 1 (R6 2-edge form) + theta1 + node_prep2 -----
// P2 written as fp16 (8 halves = 16 B/row) for gather2's random reads.
__global__ __launch_bounds__(256) void gather1_fused(
    const int* __restrict__ off, const int* __restrict__ deg,
    const uint2* __restrict__ fin, const float4* __restrict__ wedge1,
    const __half* __restrict__ x_h, const float* __restrict__ h1,
    const float* __restrict__ theta1,
    const float* __restrict__ root2, const float* __restrict__ theta2,
    const float* __restrict__ bias2,
    float* __restrict__ o2, __half* __restrict__ P2h, int N)
{
    __shared__ float th[4 * 64 * 21];
    __shared__ float w2s[200];
    __shared__ float w2b[2];
    int tid = threadIdx.x;
    for (int i = tid; i < 5120; i += 256) {
        int l = i / 1280, f = (i / 20) % 64, h = i % 20;
        th[(l*64 + f)*21 + h] = theta1[i];
    }
    for (int i = tid; i < 200; i += 256) {
        int o = i / 20, h = i % 20;
        float v;
        if (o < 2) v = root2[h*2 + o];
        else { int l = (o-2) >> 1, jj = (o-2) & 1; v = theta2[l*40 + h*2 + jj]; }
        w2s[i] = v;
    }
    if (tid < 2) w2b[tid] = bias2[tid];
    __syncthreads();
    int t = blockIdx.x * 256 + tid;
    int n = t >> 3, q = t & 7;
    if (n >= N) return;
    int start = off[n];
    int c = deg[n];
    const uint2* sl = fin + start;
    float acc[4][8];
    #pragma unroll
    for (int l = 0; l < 4; ++l)
        #pragma unroll
        for (int j = 0; j < 8; ++j) acc[l][j] = 0.f;
    int half = (c + 1) >> 1;
    for (int i = 0; i < half; ++i) {
        uint2 e1 = sl[i];
        int has2 = (i + half) < c;
        uint2 e2 = has2 ? sl[i + half] : e1;
        int nbr1 = (int)e1.x, nbr2 = (int)e2.x;
        unsigned we1 = e1.y & 0x3FFFFFu, we2 = e2.y & 0x3FFFFFu;
        float4 w1 = wedge1[we1];
        float4 w2 = wedge1[we2];
        float z = has2 ? 1.f : 0.f;
        w2.x *= z; w2.y *= z; w2.z *= z; w2.w *= z;
        uint4 hx1 = *(const uint4*)(x_h + (size_t)nbr1*64 + q*8);
        uint4 hx2 = *(const uint4*)(x_h + (size_t)nbr2*64 + q*8);
        const __half* hp1 = (const __half*)&hx1;
        const __half* hp2 = (const __half*)&hx2;
        #pragma unroll
        for (int j2 = 0; j2 < 8; ++j2) {
            float xa = __half2float(hp1[j2]);
            float xb = __half2float(hp2[j2]);
            acc[0][j2] += w1.x * xa + w2.x * xb;
            acc[1][j2] += w1.y * xa + w2.y * xb;
            acc[2][j2] += w1.z * xa + w2.z * xb;
            acc[3][j2] += w1.w * xa + w2.w * xb;
        }
    }
    float p[20];
    #pragma unroll
    for (int h = 0; h < 20; ++h) p[h] = 0.f;
    #pragma unroll
    for (int l = 0; l < 4; ++l) {
        #pragma unroll
        for (int j2 = 0; j2 < 8; ++j2) {
            float a = acc[l][j2];
            int base = ((l << 6) + (q << 3) + j2) * 21;
            #pragma unroll
            for (int h = 0; h < 20; ++h) p[h] += a * th[base + h];
        }
    }
    #pragma unroll
    for (int m = 1; m < 8; m <<= 1) {
        #pragma unroll
        for (int h = 0; h < 20; ++h) p[h] += __shfl_xor(p[h], m, 64);
    }
    const float4* hb = (const float4*)(h1 + (size_t)n*20);
    float hv[20];
    #pragma unroll
    for (int qq = 0; qq < 5; ++qq) {
        float4 v = hb[qq];
        hv[qq*4+0] = fmaxf(p[qq*4+0] + v.x, 0.f);
        hv[qq*4+1] = fmaxf(p[qq*4+1] + v.y, 0.f);
        hv[qq*4+2] = fmaxf(p[qq*4+2] + v.z, 0.f);
        hv[qq*4+3] = fmaxf(p[qq*4+3] + v.w, 0.f);
    }
    for (int o = q; o < 10; o += 8) {
        float v = (o < 2) ? w2b[o] : 0.f;
        #pragma unroll
        for (int h = 0; h < 20; ++h) v += hv[h] * w2s[o*20 + h];
        if (o < 2) o2[(size_t)n*2 + o] = v;
        else       P2h[(size_t)n*8 + (o - 2)] = __float2half(v);
    }
}

// ---------------- K7: gather layer 2 (8 lanes/node, fp16 P2) + log_softmax ------
__global__ __launch_bounds__(256) void gather2_lsm_kernel(
    const int* __restrict__ off, const int* __restrict__ deg,
    const uint2* __restrict__ fin, const float4* __restrict__ wedge2,
    const __half* __restrict__ P2h, const float* __restrict__ o2,
    float* __restrict__ out, int N)
{
    int t = blockIdx.x * 256 + threadIdx.x;
    int n = t >> 3, r = t & 7;
    if (n >= N) return;
    int start = off[n];
    int c = deg[n];
    const uint2* sl = fin + start;
    float o0 = 0.f, o1 = 0.f;
    for (int i = r; i < c; i += 8) {
        uint2 en = sl[i];
        int nbr = (int)en.x;
        unsigned we = en.y & 0x3FFFFFu;
        float4 w = wedge2[we];
        uint4 hx = *(const uint4*)(P2h + (size_t)nbr * 8);
        const __half* ph = (const __half*)&hx;
        o0 += w.x*__half2float(ph[0]) + w.y*__half2float(ph[2])
            + w.z*__half2float(ph[4]) + w.w*__half2float(ph[6]);
        o1 += w.x*__half2float(ph[1]) + w.y*__half2float(ph[3])
            + w.z*__half2float(ph[5]) + w.w*__half2float(ph[7]);
    }
    #pragma unroll
    for (int m = 1; m < 8; m <<= 1) {
        o0 += __shfl_xor(o0, m, 64);
        o1 += __shfl_xor(o1, m, 64);
    }
    if (r == 0) {
        o0 += o2[(size_t)n*2];
        o1 += o2[(size_t)n*2 + 1];
        float mx = fmaxf(o0, o1);
        float lse = mx + logf(expf(o0 - mx) + expf(o1 - mx));
        out[(size_t)n*2]     = o0 - lse;
        out[(size_t)n*2 + 1] = o1 - lse;
    }
}

// ================= Fallback path (atomic scatter, R1-style) =====================
__global__ __launch_bounds__(256) void node_prep1(
    const float* __restrict__ x, const float* __restrict__ root1,
    const float* __restrict__ theta1, const float* __restrict__ bias1,
    float* __restrict__ h1, float* __restrict__ P1, int N)
{
    __shared__ float Ws[64 * 100];
    __shared__ float xs[8 * 64];
    __shared__ float sb[20];
    int tid = threadIdx.x;
    for (int i = tid; i < 6400; i += 256) {
        int f = i / 100, c = i % 100;
        float v;
        if (c < 20) v = root1[f*20 + c];
        else { int l = (c-20)/20, hh = (c-20)%20; v = theta1[l*1280 + f*20 + hh]; }
        Ws[i] = v;
    }
    if (tid < 20) sb[tid] = bias1[tid];
    int nb = blockIdx.x * 8;
    for (int i = tid; i < 512; i += 256) {
        int nl = i >> 6, f = i & 63;
        int n = nb + nl;
        xs[i] = (n < N) ? x[(size_t)n*64 + f] : 0.f;
    }
    __syncthreads();
    for (int i = tid; i < 800; i += 256) {
        int nl = i / 100, c = i % 100;
        int n = nb + nl;
        if (n >= N) continue;
        float acc = 0.f;
        #pragma unroll 16
        for (int f = 0; f < 64; ++f) acc += xs[nl*64 + f] * Ws[f*100 + c];
        if (c < 20) h1[(size_t)n*20 + c] = acc + sb[c];
        else        P1[(size_t)n*80 + (c - 20)] = acc;
    }
}

__global__ __launch_bounds__(256) void edge_scatter1(
    const int* __restrict__ ei, const float4* __restrict__ wedge1,
    const float4* __restrict__ P1, float* __restrict__ h1, int E)
{
    int e = blockIdx.x * 256 + threadIdx.x;
    if (e >= E) return;
    int s = ei[e], d = ei[E + e];
    float4 w = wedge1[e];
    const float4* Ps = P1 + (size_t)s * 20;
    const float4* Pd = P1 + (size_t)d * 20;
    float* Hs = h1 + (size_t)s * 20;
    float* Hd = h1 + (size_t)d * 20;
    #pragma unroll
    for (int q = 0; q < 5; ++q) {
        float4 a0 = Ps[q], a1 = Ps[5+q], a2 = Ps[10+q], a3 = Ps[15+q];
        atomicAdd(Hd + q*4 + 0, w.x*a0.x + w.y*a1.x + w.z*a2.x + w.w*a3.x);
        atomicAdd(Hd + q*4 + 1, w.x*a0.y + w.y*a1.y + w.z*a2.y + w.w*a3.y);
        atomicAdd(Hd + q*4 + 2, w.x*a0.z + w.y*a1.z + w.z*a2.z + w.w*a3.z);
        atomicAdd(Hd + q*4 + 3, w.x*a0.w + w.y*a1.w + w.z*a2.w + w.w*a3.w);
        float4 b0 = Pd[q], b1 = Pd[5+q], b2 = Pd[10+q], b3 = Pd[15+q];
        atomicAdd(Hs + q*4 + 0, w.x*b0.x + w.y*b1.x + w.z*b2.x + w.w*b3.x);
        atomicAdd(Hs + q*4 + 1, w.x*b0.y + w.y*b1.y + w.z*b2.y + w.w*b3.y);
        atomicAdd(Hs + q*4 + 2, w.x*b0.z + w.y*b1.z + w.z*b2.z + w.w*b3.z);
        atomicAdd(Hs + q*4 + 3, w.x*b0.w + w.y*b1.w + w.z*b2.w + w.w*b3.w);
    }
}

__global__ __launch_bounds__(256) void node_prep2(
    const float* __restrict__ h1, const float* __restrict__ root2,
    const float* __restrict__ theta2, const float* __restrict__ bias2,
    float* __restrict__ out2, float* __restrict__ P2, int N)
{
    __shared__ float sr[40], st[160], sb2[2];
    int tid = threadIdx.x;
    if (tid < 40) sr[tid] = root2[tid];
    if (tid >= 64 && tid < 224) st[tid - 64] = theta2[tid - 64];
    if (tid < 2) sb2[tid] = bias2[tid];
    __syncthreads();
    int n = blockIdx.x * 256 + tid;
    if (n >= N) return;
    float hv[20];
    const float4* hp = (const float4*)(h1 + (size_t)n * 20);
    #pragma unroll
    for (int q = 0; q < 5; ++q) {
        float4 v = hp[q];
        hv[q*4+0] = fmaxf(v.x, 0.f);
        hv[q*4+1] = fmaxf(v.y, 0.f);
        hv[q*4+2] = fmaxf(v.z, 0.f);
        hv[q*4+3] = fmaxf(v.w, 0.f);
    }
    float o0 = sb2[0], o1 = sb2[1];
    #pragma unroll
    for (int h = 0; h < 20; ++h) { o0 += hv[h]*sr[h*2]; o1 += hv[h]*sr[h*2+1]; }
    out2[(size_t)n*2 + 0] = o0;
    out2[(size_t)n*2 + 1] = o1;
    #pragma unroll
    for (int l = 0; l < 4; ++l) {
        float p0 = 0.f, p1 = 0.f;
        #pragma unroll
        for (int h = 0; h < 20; ++h) {
            p0 += hv[h]*st[l*40 + h*2];
            p1 += hv[h]*st[l*40 + h*2 + 1];
        }
        P2[(size_t)n*8 + l*2 + 0] = p0;
        P2[(size_t)n*8 + l*2 + 1] = p1;
    }
}

__global__ __launch_bounds__(256) void edge_scatter2(
    const int* __restrict__ ei, const float4* __restrict__ wedge2,
    const float4* __restrict__ P2, float* __restrict__ out2, int E)
{
    int e = blockIdx.x * 256 + threadIdx.x;
    if (e >= E) return;
    int s = ei[e], d = ei[E + e];
    float4 w = wedge2[e];
    float4 pa = P2[(size_t)s*2], pb = P2[(size_t)s*2 + 1];
    float y0 = w.x*pa.x + w.y*pa.z + w.z*pb.x + w.w*pb.z;
    float y1 = w.x*pa.y + w.y*pa.w + w.z*pb.y + w.w*pb.w;
    atomicAdd(out2 + (size_t)d*2 + 0, y0);
    atomicAdd(out2 + (size_t)d*2 + 1, y1);
    float4 qa = P2[(size_t)d*2], qb = P2[(size_t)d*2 + 1];
    float z0 = w.x*qa.x + w.y*qa.z + w.z*qb.x + w.w*qb.z;
    float z1 = w.x*qa.y + w.y*qa.w + w.z*qb.y + w.w*qb.w;
    atomicAdd(out2 + (size_t)s*2 + 0, z0);
    atomicAdd(out2 + (size_t)s*2 + 1, z1);
}

__global__ __launch_bounds__(256) void logsoftmax_k(
    const float* __restrict__ out2, float* __restrict__ out, int N)
{
    int n = blockIdx.x * 256 + threadIdx.x;
    if (n >= N) return;
    float o0 = out2[(size_t)n*2], o1 = out2[(size_t)n*2 + 1];
    float m = fmaxf(o0, o1);
    float lse = m + logf(expf(o0 - m) + expf(o1 - m));
    out[(size_t)n*2]     = o0 - lse;
    out[(size_t)n*2 + 1] = o1 - lse;
}

extern "C" void kernel_launch(void* const* d_in, const int* in_sizes, int n_in,
                              void* d_out, int out_size, void* d_ws, size_t ws_size,
                              hipStream_t stream)
{
    const float* x     = (const float*)d_in[0];
    const int*   ei    = (const int*)d_in[1];
    const float* attr  = (const float*)d_in[2];
    const float* cut   = (const float*)d_in[3];
    const float* cw1   = (const float*)d_in[4];
    const float* cb1   = (const float*)d_in[5];
    const float* f1w1  = (const float*)d_in[6];
    const float* f1b1  = (const float*)d_in[7];
    const float* f2w1  = (const float*)d_in[8];
    const float* f2b1  = (const float*)d_in[9];
    const float* th1   = (const float*)d_in[10];
    const float* rt1   = (const float*)d_in[11];
    const float* bs1   = (const float*)d_in[12];
    const float* cw2   = (const float*)d_in[13];
    const float* cb2   = (const float*)d_in[14];
    const float* f1w2  = (const float*)d_in[15];
    const float* f1b2  = (const float*)d_in[16];
    const float* f2w2  = (const float*)d_in[17];
    const float* f2b2  = (const float*)d_in[18];
    const float* th2   = (const float*)d_in[19];
    const float* rt2   = (const float*)d_in[20];
    const float* bs2   = (const float*)d_in[21];

    const int N = in_sizes[0] / 64;
    const int E = in_sizes[1] / 2;
    const int M = 2 * E;
    const int NB = (N + 127) >> SHIFT;

    // ---- workspace layout (words) ----
    size_t W = 0;
    float* ws = (float*)d_ws;
    float* wedge1 = ws + W;            W += (size_t)E * 4;
    float* wedge2 = ws + W;            W += (size_t)E * 4;
    uint2* tmp    = (uint2*)(ws + W);  W += (size_t)NB * BCAP * 2;  // padded buckets
    int* off      = (int*)(ws + W);    W += N;
    int* deg      = (int*)(ws + W);    W += N;
    int* bcur     = (int*)(ws + W);    W += NB;
    W = (W + 31) & ~(size_t)31;
    __half* x_h = (__half*)(ws + W);               // 32N words
    float*  h1  = ws + W + (size_t)N * 32;         // 20N
    __half* P2h = (__half*)(ws + W + (size_t)N * 52); // 4N words (8 halves/node)
    float*  o2  = ws + W + (size_t)N * 56;         // 2N
    size_t need_new = W + (size_t)N * 58;

    bool okNew = (NB <= NB_MAX) && (E <= 0x3FFFFF) && (ws_size / 4 >= need_new);

    if (okNew) {
        filter_kernel<<<(E + 255) / 256, 256, 0, stream>>>(
            attr, cut, cw1, cb1, f1w1, f1b1, f2w1, f2b1,
            cw2, cb2, f1w2, f1b2, f2w2, f2b2, wedge1, wedge2, bcur, NB, E);
        passB_kernel<<<(M + CHUNKB - 1) / CHUNKB, 256, 0, stream>>>(
            ei, bcur, tmp, E, M, NB);
        passC_kernel<<<NB, 256, 0, stream>>>(tmp, bcur, off, deg, N);
        node_prep1b<<<(N * 8 + 255) / 256, 256, 0, stream>>>(x, rt1, bs1, h1, x_h, N);
        gather1_fused<<<(N * 8 + 255) / 256, 256, 0, stream>>>(
            off, deg, tmp, (const float4*)wedge1, x_h, h1,
            th1, rt2, th2, bs2, o2, P2h, N);
        gather2_lsm_kernel<<<(N * 8 + 255) / 256, 256, 0, stream>>>(
            off, deg, tmp, (const float4*)wedge2, P2h, o2,
            (float*)d_out, N);
    } else {
        // Fallback: atomic scatter (correct but slow). Independent layout.
        float* fw1 = ws;                           // 4E
        float* fw2 = fw1 + (size_t)E * 4;          // 4E
        float* P1  = fw2 + (size_t)E * 4;          // 80N
        float* fh1 = P1  + (size_t)N * 80;         // 20N
        float* fP2 = fh1 + (size_t)N * 20;         // 8N
        float* fo2 = fP2 + (size_t)N * 8;          // 2N
        int*   fbc = (int*)(fo2 + (size_t)N * 2);  // NB (dummy bcur target)
        filter_kernel<<<(E + 255) / 256, 256, 0, stream>>>(
            attr, cut, cw1, cb1, f1w1, f1b1, f2w1, f2b1,
            cw2, cb2, f1w2, f1b2, f2w2, f2b2, fw1, fw2, fbc,
            NB <= NB_MAX ? NB : NB_MAX, E);
        node_prep1<<<(N + 7) / 8, 256, 0, stream>>>(x, rt1, th1, bs1, fh1, P1, N);
        edge_scatter1<<<(E + 255) / 256, 256, 0, stream>>>(
            ei, (const float4*)fw1, (const float4*)P1, fh1, E);
        node_prep2<<<(N + 255) / 256, 256, 0, stream>>>(fh1, rt2, th2, bs2, fo2, fP2, N);
        edge_scatter2<<<(E + 255) / 256, 256, 0, stream>>>(
            ei, (const float4*)fw2, (const float4*)fP2, fo2, E);
        logsoftmax_k<<<(N + 255) / 256, 256, 0, stream>>>(fo2, (float*)d_out, N);
    }
}

// Round 9
// 602.423 us; speedup vs baseline: 1.1313x; 1.0180x over previous
//
#include <hip/hip_runtime.h>
#include <hip/hip_fp16.h>
#include <math.h>

// Problem constants: F_IN=64, K=16, C=20, L=4, H1=20, H2=2
// N=100k nodes, E=1.6M undirected edges, M=2E=3.2M directed entries.
//
// R8 conclusions: gather1 pinned at ~2.4-2.6 TB/s random-line ceiling (leave);
// filter is LDS-instruction-issue bound (~1000 wave-uniform ds_read_b32/edge).
// R9: vectorize filter's uniform LDS reads to float4 (~2.7x fewer LDS instrs)
// and fuse node_prep1b into the filter launch via block-range split.

#define SHIFT   7
#define NB_MAX  1024
#define CHUNKB  6144
#define BCAP    4608

// ---------------- K1: fused filter nets (vectorized LDS) + node_prep1b ----------
// Blocks [0, FB): filter one edge/thread (+ bcur init).
// Blocks [FB, FB+PB): h1 = x@root1+bias1 ; x_h = fp16(x), 8 lanes/node.
__global__ __launch_bounds__(256) void filter_prep_kernel(
    const float* __restrict__ attr, const float* __restrict__ cutoffs,
    const float* __restrict__ cw1, const float* __restrict__ cb1,
    const float* __restrict__ f1w1, const float* __restrict__ f1b1,
    const float* __restrict__ f2w1, const float* __restrict__ f2b1,
    const float* __restrict__ cw2, const float* __restrict__ cb2,
    const float* __restrict__ f1w2, const float* __restrict__ f1b2,
    const float* __restrict__ f2w2, const float* __restrict__ f2b2,
    float* __restrict__ wedge1, float* __restrict__ wedge2,
    int* __restrict__ bcur, int NB, int E,
    const float* __restrict__ x, const float* __restrict__ root1,
    const float* __restrict__ bias1, float* __restrict__ h1,
    __half* __restrict__ x_h, int N, int FB)
{
    int tid = threadIdx.x;
    if ((int)blockIdx.x >= FB) {
        // ---------------- node_prep1b body ----------------
        __shared__ float r1s[64 * 21];
        __shared__ float sb[20];
        for (int i = tid; i < 1280; i += 256) {
            int f = i / 20, h = i % 20;
            r1s[f*21 + h] = root1[i];
        }
        if (tid < 20) sb[tid] = bias1[tid];
        __syncthreads();
        int t = ((int)blockIdx.x - FB) * 256 + tid;
        int n = t >> 3, q = t & 7;
        if (n >= N) return;
        const float4* xr = (const float4*)(x + (size_t)n*64 + q*8);
        float4 va = xr[0], vb = xr[1];
        float xf[8] = {va.x, va.y, va.z, va.w, vb.x, vb.y, vb.z, vb.w};
        __half hh[8];
        #pragma unroll
        for (int j = 0; j < 8; ++j) hh[j] = __float2half(xf[j]);
        *(uint4*)(x_h + (size_t)n*64 + q*8) = *(const uint4*)hh;
        float p[20];
        #pragma unroll
        for (int h = 0; h < 20; ++h) p[h] = 0.f;
        #pragma unroll
        for (int j = 0; j < 8; ++j) {
            float xv = xf[j];
            int base = (q*8 + j) * 21;
            #pragma unroll
            for (int h = 0; h < 20; ++h) p[h] += xv * r1s[base + h];
        }
        #pragma unroll
        for (int m = 1; m < 8; m <<= 1) {
            #pragma unroll
            for (int h = 0; h < 20; ++h) p[h] += __shfl_xor(p[h], m, 64);
        }
        if (q < 5) {
            float4 o;
            o.x = p[q*4+0] + sb[q*4+0];
            o.y = p[q*4+1] + sb[q*4+1];
            o.z = p[q*4+2] + sb[q*4+2];
            o.w = p[q*4+3] + sb[q*4+3];
            *(float4*)(h1 + (size_t)n*20 + q*4) = o;
        }
        return;
    }
    // ---------------- filter body ----------------
    __shared__ float s_cut[16];
    __shared__ float s_w[2][344]; // cw(120) cb(20) f1w(160) f1b(8) f2w(32) f2b(4)
    __shared__ float tab[2 * 20 * 64];
    int gb = blockIdx.x * 256 + tid;
    if (gb < NB) bcur[gb] = gb * BCAP;
    if (tid < 16) s_cut[tid] = cutoffs[tid];
    for (int i = tid; i < 344; i += 256) {
        float v1, v2;
        if (i < 120)      { v1 = cw1[i];       v2 = cw2[i]; }
        else if (i < 140) { v1 = cb1[i-120];   v2 = cb2[i-120]; }
        else if (i < 300) { v1 = f1w1[i-140];  v2 = f1w2[i-140]; }
        else if (i < 308) { v1 = f1b1[i-300];  v2 = f1b2[i-300]; }
        else if (i < 340) { v1 = f2w1[i-308];  v2 = f2w2[i-308]; }
        else              { v1 = f2b1[i-340];  v2 = f2b2[i-340]; }
        s_w[0][i] = v1; s_w[1][i] = v2;
    }
    __syncthreads();
    if (tid < 40) {
        int l = tid / 20, ch = tid % 20;
        const float* W = s_w[l];
        float w00 = W[ch*6+0], w01 = W[ch*6+1], w02 = W[ch*6+2];
        float w10 = W[ch*6+3], w11 = W[ch*6+4], w12 = W[ch*6+5];
        float b = W[120 + ch];
        float* tb = &tab[(l*20 + ch) * 64];
        tb[0]  = w01*s_cut[0]  + w02*s_cut[1];
        for (int k = 1; k <= 14; ++k)
            tb[k] = w00*s_cut[k-1] + w01*s_cut[k] + w02*s_cut[k+1];
        tb[15] = w00*s_cut[14] + w01*s_cut[15];
        float pm = tb[1]; tb[16+1] = pm;
        for (int j = 2; j <= 14; ++j) { pm = fminf(pm, tb[j]); tb[16+j] = pm; }
        float qm = tb[14]; tb[32+14] = qm;
        for (int j = 13; j >= 1; --j) { qm = fminf(qm, tb[j]); tb[32+j] = qm; }
        // float4-packed constants:
        tb[48] = w00 + w01 + w02;   // S
        tb[49] = w01 + w02;         // Sd0
        tb[50] = w00 + w01;         // S15
        tb[51] = w10 + w11 + w12;   // W3
        tb[52] = w10 + w11;         // W2
        tb[53] = w10;
        tb[54] = w11;
        tb[55] = w12;
        tb[56] = b;
        tb[57] = tb[0];             // T0 copy
        tb[58] = tb[15];            // T15 copy
        tb[59] = 0.f;
    }
    __syncthreads();
    int e = gb;
    if (e >= E) return;

    float a = attr[e];
    int idx = 0;
    #pragma unroll
    for (int k = 0; k < 16; ++k) idx += (a > s_cut[k]) ? 1 : 0;

    #pragma unroll
    for (int layer = 0; layer < 2; ++layer) {
        const float* W = s_w[layer];
        float h[20];
        #pragma unroll
        for (int c = 0; c < 20; ++c) {
            const float* tb = &tab[(layer*20 + c) * 64];
            const float4* tb4 = (const float4*)tb;
            float4 A  = tb4[12];   // S, Sd0, S15, W3
            float4 B  = tb4[13];   // W2, w10, w11, w12
            float4 Cv = tb4[14];   // b, T0, T15, 0
            float b = Cv.x;
            float base = fmaf(A.x, a, b);
            float y0 = fmaf(A.y, a, b) - Cv.y;
            y0 += (idx >= 1 ? B.z : 0.f) + (idx >= 2 ? B.w : 0.f);
            float m = y0;
            float y15 = fmaf(A.z, a, b) - Cv.z;
            y15 += (idx >= 15 ? B.y : 0.f) + (idx >= 16 ? B.z : 0.f);
            m = fmaxf(m, y15);
            {
                int j = idx - 2; j = j > 14 ? 14 : j;
                float v = base + A.w - tb[16 + j];
                m = (idx >= 3) ? fmaxf(m, v) : m;
            }
            {
                float v = base + B.x - tb[(idx >= 2 && idx <= 15) ? (idx-1) : 1];
                m = (idx >= 2 && idx <= 15) ? fmaxf(m, v) : m;
            }
            {
                float v = base + B.y - tb[(idx >= 1 && idx <= 14) ? idx : 1];
                m = (idx >= 1 && idx <= 14) ? fmaxf(m, v) : m;
            }
            {
                int j = idx + 1; j = j < 1 ? 1 : j;
                float v = base - tb[32 + (j > 14 ? 14 : j)];
                m = (idx <= 13) ? fmaxf(m, v) : m;
            }
            h[c] = fmaxf(m, 0.f);
        }
        float g[8];
        {
            const float4* bj4 = (const float4*)&W[300];
            float4 bj0 = bj4[0], bj1 = bj4[1];
            float bj[8] = {bj0.x,bj0.y,bj0.z,bj0.w,bj1.x,bj1.y,bj1.z,bj1.w};
            #pragma unroll
            for (int j = 0; j < 8; ++j) {
                const float4* wj = (const float4*)&W[140 + j*20];
                float4 q0=wj[0], q1=wj[1], q2=wj[2], q3=wj[3], q4=wj[4];
                float t = bj[j];
                t += q0.x*h[0]  + q0.y*h[1]  + q0.z*h[2]  + q0.w*h[3];
                t += q1.x*h[4]  + q1.y*h[5]  + q1.z*h[6]  + q1.w*h[7];
                t += q2.x*h[8]  + q2.y*h[9]  + q2.z*h[10] + q2.w*h[11];
                t += q3.x*h[12] + q3.y*h[13] + q3.z*h[14] + q3.w*h[15];
                t += q4.x*h[16] + q4.y*h[17] + q4.z*h[18] + q4.w*h[19];
                g[j] = fmaxf(t, 0.f);
            }
        }
        float4 wo;
        float* wp = (float*)&wo;
        {
            const float4* bl4 = (const float4*)&W[340];
            float4 bl = bl4[0];
            float blv[4] = {bl.x, bl.y, bl.z, bl.w};
            #pragma unroll
            for (int l = 0; l < 4; ++l) {
                const float4* wl = (const float4*)&W[308 + l*8];
                float4 r0 = wl[0], r1 = wl[1];
                float t = blv[l];
                t += r0.x*g[0] + r0.y*g[1] + r0.z*g[2] + r0.w*g[3];
                t += r1.x*g[4] + r1.y*g[5] + r1.z*g[6] + r1.w*g[7];
                wp[l] = fmaxf(t, 0.f);
            }
        }
        float4* dstp = (float4*)(layer == 0 ? wedge1 : wedge2);
        dstp[e] = wo;
    }
}

// ---------------- K3: scatter directed entries into capacity buckets ------------
// entry.x = nbr node; entry.y = edge-id | (own&127)<<22
__global__ __launch_bounds__(256) void passB_kernel(
    const int* __restrict__ ei, int* __restrict__ bcur, uint2* __restrict__ tmp,
    int E, int M, int NB)
{
    __shared__ int hist[NB_MAX];
    __shared__ int lbase[NB_MAX];
    __shared__ int gpos[NB_MAX];
    __shared__ int aux[256];
    __shared__ uint2 stage[CHUNKB];
    int tid = threadIdx.x;
    int start = blockIdx.x * CHUNKB;
    if (start >= M) return;
    int cnt = M - start; if (cnt > CHUNKB) cnt = CHUNKB;
    for (int i = tid; i < NB_MAX; i += 256) hist[i] = 0;
    __syncthreads();
    for (int i = tid; i < cnt; i += 256) {
        int de = start + i;
        int own = ei[de < E ? de + E : de - E];
        atomicAdd(&hist[own >> SHIFT], 1);
    }
    __syncthreads();
    {   // exclusive scan hist[0..1023] -> lbase, 256 threads x 4 items
        int t4 = tid * 4;
        int a0 = hist[t4], a1 = hist[t4+1], a2 = hist[t4+2], a3 = hist[t4+3];
        aux[tid] = a0 + a1 + a2 + a3;
        __syncthreads();
        for (int off = 1; off < 256; off <<= 1) {
            int v = (tid >= off) ? aux[tid - off] : 0;
            __syncthreads();
            aux[tid] += v;
            __syncthreads();
        }
        int te = (tid == 0) ? 0 : aux[tid - 1];
        lbase[t4]   = te;
        lbase[t4+1] = te + a0;
        lbase[t4+2] = te + a0 + a1;
        lbase[t4+3] = te + a0 + a1 + a2;
    }
    __syncthreads();
    for (int b = tid; b < NB; b += 256) {
        int cb = hist[b];
        gpos[b] = cb ? atomicAdd(&bcur[b], cb) : 0;
    }
    __syncthreads();
    for (int i = tid; i < NB_MAX; i += 256) hist[i] = 0;  // reuse as cursor
    __syncthreads();
    for (int i = tid; i < cnt; i += 256) {
        int de = start + i;
        int j = de < E ? de : de - E;
        int own = ei[de < E ? de + E : de - E];
        unsigned nbr = (unsigned)ei[de];
        int b = own >> SHIFT;
        int p = atomicAdd(&hist[b], 1);
        stage[lbase[b] + p] = make_uint2(nbr, (unsigned)j | ((unsigned)(own & 127) << 22));
    }
    __syncthreads();
    int wave = tid >> 6, lane = tid & 63;
    for (int b = wave; b < NB; b += 4) {
        int n_b = hist[b];
        if (!n_b) continue;
        int lo = lbase[b], g = gpos[b];
        int lim = (b + 1) * BCAP;          // capacity guard (statistically never hit)
        for (int k = lane; k < n_b; k += 64) {
            if (g + k < lim) tmp[(size_t)g + k] = stage[lo + k];
        }
    }
}

// ---------------- K4: per-bucket node sort in place -> (off, deg) ---------------
__global__ __launch_bounds__(256) void passC_kernel(
    uint2* __restrict__ tmp, const int* __restrict__ bcur,
    int* __restrict__ off, int* __restrict__ deg, int N)
{
    __shared__ uint2 ordered[BCAP];
    __shared__ int hist[128], nexcl[128], cur[128], s2[128];
    int tid = threadIdx.x;
    int b = blockIdx.x;
    int lo = b * BCAP;
    int cnt = bcur[b] - lo;
    if (cnt > BCAP) cnt = BCAP;
    if (tid < 128) hist[tid] = 0;
    __syncthreads();
    for (int i = tid; i < cnt; i += 256)
        atomicAdd(&hist[(tmp[(size_t)lo + i].y >> 22) & 127], 1);
    __syncthreads();
    if (tid < 128) s2[tid] = hist[tid];
    __syncthreads();
    for (int o = 1; o < 128; o <<= 1) {
        int v = (tid < 128 && tid >= o) ? s2[tid - o] : 0;
        __syncthreads();
        if (tid < 128) s2[tid] += v;
        __syncthreads();
    }
    if (tid < 128) {
        int excl = s2[tid] - hist[tid];
        nexcl[tid] = excl;
        cur[tid] = 0;
        int node = (b << SHIFT) + tid;
        if (node < N) { off[node] = lo + excl; deg[node] = hist[tid]; }
    }
    __syncthreads();
    for (int i = tid; i < cnt; i += 256) {
        uint2 en = tmp[(size_t)lo + i];
        int ol = (en.y >> 22) & 127;
        int p = atomicAdd(&cur[ol], 1);
        ordered[nexcl[ol] + p] = en;
    }
    __syncthreads();
    for (int i = tid; i < cnt; i += 256) tmp[(size_t)lo + i] = ordered[i];
}

// ---------------- K6: gather layer 1 (2-edge) + theta1 + fused node_prep2 -------
// P2 written as fp16 (8 halves = 16 B/row) for gather2's random reads.
__global__ __launch_bounds__(256) void gather1_fused(
    const int* __restrict__ off, const int* __restrict__ deg,
    const uint2* __restrict__ fin, const float4* __restrict__ wedge1,
    const __half* __restrict__ x_h, const float* __restrict__ h1,
    const float* __restrict__ theta1,
    const float* __restrict__ root2, const float* __restrict__ theta2,
    const float* __restrict__ bias2,
    float* __restrict__ o2, __half* __restrict__ P2h, int N)
{
    __shared__ float th[4 * 64 * 21];
    __shared__ float w2s[200];
    __shared__ float w2b[2];
    int tid = threadIdx.x;
    for (int i = tid; i < 5120; i += 256) {
        int l = i / 1280, f = (i / 20) % 64, h = i % 20;
        th[(l*64 + f)*21 + h] = theta1[i];
    }
    for (int i = tid; i < 200; i += 256) {
        int o = i / 20, h = i % 20;
        float v;
        if (o < 2) v = root2[h*2 + o];
        else { int l = (o-2) >> 1, jj = (o-2) & 1; v = theta2[l*40 + h*2 + jj]; }
        w2s[i] = v;
    }
    if (tid < 2) w2b[tid] = bias2[tid];
    __syncthreads();
    int t = blockIdx.x * 256 + tid;
    int n = t >> 3, q = t & 7;
    if (n >= N) return;
    int start = off[n];
    int c = deg[n];
    const uint2* sl = fin + start;
    float acc[4][8];
    #pragma unroll
    for (int l = 0; l < 4; ++l)
        #pragma unroll
        for (int j = 0; j < 8; ++j) acc[l][j] = 0.f;
    int half = (c + 1) >> 1;
    for (int i = 0; i < half; ++i) {
        uint2 e1 = sl[i];
        int has2 = (i + half) < c;
        uint2 e2 = has2 ? sl[i + half] : e1;
        int nbr1 = (int)e1.x, nbr2 = (int)e2.x;
        unsigned we1 = e1.y & 0x3FFFFFu, we2 = e2.y & 0x3FFFFFu;
        float4 w1 = wedge1[we1];
        float4 w2 = wedge1[we2];
        float z = has2 ? 1.f : 0.f;
        w2.x *= z; w2.y *= z; w2.z *= z; w2.w *= z;
        uint4 hx1 = *(const uint4*)(x_h + (size_t)nbr1*64 + q*8);
        uint4 hx2 = *(const uint4*)(x_h + (size_t)nbr2*64 + q*8);
        const __half* hp1 = (const __half*)&hx1;
        const __half* hp2 = (const __half*)&hx2;
        #pragma unroll
        for (int j2 = 0; j2 < 8; ++j2) {
            float xa = __half2float(hp1[j2]);
            float xb = __half2float(hp2[j2]);
            acc[0][j2] += w1.x * xa + w2.x * xb;
            acc[1][j2] += w1.y * xa + w2.y * xb;
            acc[2][j2] += w1.z * xa + w2.z * xb;
            acc[3][j2] += w1.w * xa + w2.w * xb;
        }
    }
    float p[20];
    #pragma unroll
    for (int h = 0; h < 20; ++h) p[h] = 0.f;
    #pragma unroll
    for (int l = 0; l < 4; ++l) {
        #pragma unroll
        for (int j2 = 0; j2 < 8; ++j2) {
            float a = acc[l][j2];
            int base = ((l << 6) + (q << 3) + j2) * 21;
            #pragma unroll
            for (int h = 0; h < 20; ++h) p[h] += a * th[base + h];
        }
    }
    #pragma unroll
    for (int m = 1; m < 8; m <<= 1) {
        #pragma unroll
        for (int h = 0; h < 20; ++h) p[h] += __shfl_xor(p[h], m, 64);
    }
    const float4* hb = (const float4*)(h1 + (size_t)n*20);
    float hv[20];
    #pragma unroll
    for (int qq = 0; qq < 5; ++qq) {
        float4 v = hb[qq];
        hv[qq*4+0] = fmaxf(p[qq*4+0] + v.x, 0.f);
        hv[qq*4+1] = fmaxf(p[qq*4+1] + v.y, 0.f);
        hv[qq*4+2] = fmaxf(p[qq*4+2] + v.z, 0.f);
        hv[qq*4+3] = fmaxf(p[qq*4+3] + v.w, 0.f);
    }
    for (int o = q; o < 10; o += 8) {
        float v = (o < 2) ? w2b[o] : 0.f;
        #pragma unroll
        for (int h = 0; h < 20; ++h) v += hv[h] * w2s[o*20 + h];
        if (o < 2) o2[(size_t)n*2 + o] = v;
        else       P2h[(size_t)n*8 + (o - 2)] = __float2half(v);
    }
}

// ---------------- K7: gather layer 2 (8 lanes/node, fp16 P2) + log_softmax ------
__global__ __launch_bounds__(256) void gather2_lsm_kernel(
    const int* __restrict__ off, const int* __restrict__ deg,
    const uint2* __restrict__ fin, const float4* __restrict__ wedge2,
    const __half* __restrict__ P2h, const float* __restrict__ o2,
    float* __restrict__ out, int N)
{
    int t = blockIdx.x * 256 + threadIdx.x;
    int n = t >> 3, r = t & 7;
    if (n >= N) return;
    int start = off[n];
    int c = deg[n];
    const uint2* sl = fin + start;
    float o0 = 0.f, o1 = 0.f;
    for (int i = r; i < c; i += 8) {
        uint2 en = sl[i];
        int nbr = (int)en.x;
        unsigned we = en.y & 0x3FFFFFu;
        float4 w = wedge2[we];
        uint4 hx = *(const uint4*)(P2h + (size_t)nbr * 8);
        const __half* ph = (const __half*)&hx;
        o0 += w.x*__half2float(ph[0]) + w.y*__half2float(ph[2])
            + w.z*__half2float(ph[4]) + w.w*__half2float(ph[6]);
        o1 += w.x*__half2float(ph[1]) + w.y*__half2float(ph[3])
            + w.z*__half2float(ph[5]) + w.w*__half2float(ph[7]);
    }
    #pragma unroll
    for (int m = 1; m < 8; m <<= 1) {
        o0 += __shfl_xor(o0, m, 64);
        o1 += __shfl_xor(o1, m, 64);
    }
    if (r == 0) {
        o0 += o2[(size_t)n*2];
        o1 += o2[(size_t)n*2 + 1];
        float mx = fmaxf(o0, o1);
        float lse = mx + logf(expf(o0 - mx) + expf(o1 - mx));
        out[(size_t)n*2]     = o0 - lse;
        out[(size_t)n*2 + 1] = o1 - lse;
    }
}

// ================= Fallback path (atomic scatter, R1-style) =====================
__global__ __launch_bounds__(256) void node_prep1(
    const float* __restrict__ x, const float* __restrict__ root1,
    const float* __restrict__ theta1, const float* __restrict__ bias1,
    float* __restrict__ h1, float* __restrict__ P1, int N)
{
    __shared__ float Ws[64 * 100];
    __shared__ float xs[8 * 64];
    __shared__ float sb[20];
    int tid = threadIdx.x;
    for (int i = tid; i < 6400; i += 256) {
        int f = i / 100, c = i % 100;
        float v;
        if (c < 20) v = root1[f*20 + c];
        else { int l = (c-20)/20, hh = (c-20)%20; v = theta1[l*1280 + f*20 + hh]; }
        Ws[i] = v;
    }
    if (tid < 20) sb[tid] = bias1[tid];
    int nb = blockIdx.x * 8;
    for (int i = tid; i < 512; i += 256) {
        int nl = i >> 6, f = i & 63;
        int n = nb + nl;
        xs[i] = (n < N) ? x[(size_t)n*64 + f] : 0.f;
    }
    __syncthreads();
    for (int i = tid; i < 800; i += 256) {
        int nl = i / 100, c = i % 100;
        int n = nb + nl;
        if (n >= N) continue;
        float acc = 0.f;
        #pragma unroll 16
        for (int f = 0; f < 64; ++f) acc += xs[nl*64 + f] * Ws[f*100 + c];
        if (c < 20) h1[(size_t)n*20 + c] = acc + sb[c];
        else        P1[(size_t)n*80 + (c - 20)] = acc;
    }
}

__global__ __launch_bounds__(256) void edge_scatter1(
    const int* __restrict__ ei, const float4* __restrict__ wedge1,
    const float4* __restrict__ P1, float* __restrict__ h1, int E)
{
    int e = blockIdx.x * 256 + threadIdx.x;
    if (e >= E) return;
    int s = ei[e], d = ei[E + e];
    float4 w = wedge1[e];
    const float4* Ps = P1 + (size_t)s * 20;
    const float4* Pd = P1 + (size_t)d * 20;
    float* Hs = h1 + (size_t)s * 20;
    float* Hd = h1 + (size_t)d * 20;
    #pragma unroll
    for (int q = 0; q < 5; ++q) {
        float4 a0 = Ps[q], a1 = Ps[5+q], a2 = Ps[10+q], a3 = Ps[15+q];
        atomicAdd(Hd + q*4 + 0, w.x*a0.x + w.y*a1.x + w.z*a2.x + w.w*a3.x);
        atomicAdd(Hd + q*4 + 1, w.x*a0.y + w.y*a1.y + w.z*a2.y + w.w*a3.y);
        atomicAdd(Hd + q*4 + 2, w.x*a0.z + w.y*a1.z + w.z*a2.z + w.w*a3.z);
        atomicAdd(Hd + q*4 + 3, w.x*a0.w + w.y*a1.w + w.z*a2.w + w.w*a3.w);
        float4 b0 = Pd[q], b1 = Pd[5+q], b2 = Pd[10+q], b3 = Pd[15+q];
        atomicAdd(Hs + q*4 + 0, w.x*b0.x + w.y*b1.x + w.z*b2.x + w.w*b3.x);
        atomicAdd(Hs + q*4 + 1, w.x*b0.y + w.y*b1.y + w.z*b2.y + w.w*b3.y);
        atomicAdd(Hs + q*4 + 2, w.x*b0.z + w.y*b1.z + w.z*b2.z + w.w*b3.z);
        atomicAdd(Hs + q*4 + 3, w.x*b0.w + w.y*b1.w + w.z*b2.w + w.w*b3.w);
    }
}

__global__ __launch_bounds__(256) void node_prep2(
    const float* __restrict__ h1, const float* __restrict__ root2,
    const float* __restrict__ theta2, const float* __restrict__ bias2,
    float* __restrict__ out2, float* __restrict__ P2, int N)
{
    __shared__ float sr[40], st[160], sb2[2];
    int tid = threadIdx.x;
    if (tid < 40) sr[tid] = root2[tid];
    if (tid >= 64 && tid < 224) st[tid - 64] = theta2[tid - 64];
    if (tid < 2) sb2[tid] = bias2[tid];
    __syncthreads();
    int n = blockIdx.x * 256 + tid;
    if (n >= N) return;
    float hv[20];
    const float4* hp = (const float4*)(h1 + (size_t)n * 20);
    #pragma unroll
    for (int q = 0; q < 5; ++q) {
        float4 v = hp[q];
        hv[q*4+0] = fmaxf(v.x, 0.f);
        hv[q*4+1] = fmaxf(v.y, 0.f);
        hv[q*4+2] = fmaxf(v.z, 0.f);
        hv[q*4+3] = fmaxf(v.w, 0.f);
    }
    float o0 = sb2[0], o1 = sb2[1];
    #pragma unroll
    for (int h = 0; h < 20; ++h) { o0 += hv[h]*sr[h*2]; o1 += hv[h]*sr[h*2+1]; }
    out2[(size_t)n*2 + 0] = o0;
    out2[(size_t)n*2 + 1] = o1;
    #pragma unroll
    for (int l = 0; l < 4; ++l) {
        float p0 = 0.f, p1 = 0.f;
        #pragma unroll
        for (int h = 0; h < 20; ++h) {
            p0 += hv[h]*st[l*40 + h*2];
            p1 += hv[h]*st[l*40 + h*2 + 1];
        }
        P2[(size_t)n*8 + l*2 + 0] = p0;
        P2[(size_t)n*8 + l*2 + 1] = p1;
    }
}

__global__ __launch_bounds__(256) void edge_scatter2(
    const int* __restrict__ ei, const float4* __restrict__ wedge2,
    const float4* __restrict__ P2, float* __restrict__ out2, int E)
{
    int e = blockIdx.x * 256 + threadIdx.x;
    if (e >= E) return;
    int s = ei[e], d = ei[E + e];
    float4 w = wedge2[e];
    float4 pa = P2[(size_t)s*2], pb = P2[(size_t)s*2 + 1];
    float y0 = w.x*pa.x + w.y*pa.z + w.z*pb.x + w.w*pb.z;
    float y1 = w.x*pa.y + w.y*pa.w + w.z*pb.y + w.w*pb.w;
    atomicAdd(out2 + (size_t)d*2 + 0, y0);
    atomicAdd(out2 + (size_t)d*2 + 1, y1);
    float4 qa = P2[(size_t)d*2], qb = P2[(size_t)d*2 + 1];
    float z0 = w.x*qa.x + w.y*qa.z + w.z*qb.x + w.w*qb.z;
    float z1 = w.x*qa.y + w.y*qa.w + w.z*qb.y + w.w*qb.w;
    atomicAdd(out2 + (size_t)s*2 + 0, z0);
    atomicAdd(out2 + (size_t)s*2 + 1, z1);
}

__global__ __launch_bounds__(256) void logsoftmax_k(
    const float* __restrict__ out2, float* __restrict__ out, int N)
{
    int n = blockIdx.x * 256 + threadIdx.x;
    if (n >= N) return;
    float o0 = out2[(size_t)n*2], o1 = out2[(size_t)n*2 + 1];
    float m = fmaxf(o0, o1);
    float lse = m + logf(expf(o0 - m) + expf(o1 - m));
    out[(size_t)n*2]     = o0 - lse;
    out[(size_t)n*2 + 1] = o1 - lse;
}

extern "C" void kernel_launch(void* const* d_in, const int* in_sizes, int n_in,
                              void* d_out, int out_size, void* d_ws, size_t ws_size,
                              hipStream_t stream)
{
    const float* x     = (const float*)d_in[0];
    const int*   ei    = (const int*)d_in[1];
    const float* attr  = (const float*)d_in[2];
    const float* cut   = (const float*)d_in[3];
    const float* cw1   = (const float*)d_in[4];
    const float* cb1   = (const float*)d_in[5];
    const float* f1w1  = (const float*)d_in[6];
    const float* f1b1  = (const float*)d_in[7];
    const float* f2w1  = (const float*)d_in[8];
    const float* f2b1  = (const float*)d_in[9];
    const float* th1   = (const float*)d_in[10];
    const float* rt1   = (const float*)d_in[11];
    const float* bs1   = (const float*)d_in[12];
    const float* cw2   = (const float*)d_in[13];
    const float* cb2   = (const float*)d_in[14];
    const float* f1w2  = (const float*)d_in[15];
    const float* f1b2  = (const float*)d_in[16];
    const float* f2w2  = (const float*)d_in[17];
    const float* f2b2  = (const float*)d_in[18];
    const float* th2   = (const float*)d_in[19];
    const float* rt2   = (const float*)d_in[20];
    const float* bs2   = (const float*)d_in[21];

    const int N = in_sizes[0] / 64;
    const int E = in_sizes[1] / 2;
    const int M = 2 * E;
    const int NB = (N + 127) >> SHIFT;

    // ---- workspace layout (words) ----
    size_t W = 0;
    float* ws = (float*)d_ws;
    float* wedge1 = ws + W;            W += (size_t)E * 4;
    float* wedge2 = ws + W;            W += (size_t)E * 4;
    uint2* tmp    = (uint2*)(ws + W);  W += (size_t)NB * BCAP * 2;  // padded buckets
    int* off      = (int*)(ws + W);    W += N;
    int* deg      = (int*)(ws + W);    W += N;
    int* bcur     = (int*)(ws + W);    W += NB;
    W = (W + 31) & ~(size_t)31;
    __half* x_h = (__half*)(ws + W);               // 32N words
    float*  h1  = ws + W + (size_t)N * 32;         // 20N
    __half* P2h = (__half*)(ws + W + (size_t)N * 52); // 4N words (8 halves/node)
    float*  o2  = ws + W + (size_t)N * 56;         // 2N
    size_t need_new = W + (size_t)N * 58;

    bool okNew = (NB <= NB_MAX) && (E <= 0x3FFFFF) && (ws_size / 4 >= need_new);

    if (okNew) {
        const int FB = (E + 255) / 256;
        const int PB = (N * 8 + 255) / 256;
        filter_prep_kernel<<<FB + PB, 256, 0, stream>>>(
            attr, cut, cw1, cb1, f1w1, f1b1, f2w1, f2b1,
            cw2, cb2, f1w2, f1b2, f2w2, f2b2, wedge1, wedge2, bcur, NB, E,
            x, rt1, bs1, h1, x_h, N, FB);
        passB_kernel<<<(M + CHUNKB - 1) / CHUNKB, 256, 0, stream>>>(
            ei, bcur, tmp, E, M, NB);
        passC_kernel<<<NB, 256, 0, stream>>>(tmp, bcur, off, deg, N);
        gather1_fused<<<(N * 8 + 255) / 256, 256, 0, stream>>>(
            off, deg, tmp, (const float4*)wedge1, x_h, h1,
            th1, rt2, th2, bs2, o2, P2h, N);
        gather2_lsm_kernel<<<(N * 8 + 255) / 256, 256, 0, stream>>>(
            off, deg, tmp, (const float4*)wedge2, P2h, o2,
            (float*)d_out, N);
    } else {
        // Fallback: atomic scatter (correct but slow). Independent layout.
        float* fw1 = ws;                           // 4E
        float* fw2 = fw1 + (size_t)E * 4;          // 4E
        float* P1  = fw2 + (size_t)E * 4;          // 80N
        float* fh1 = P1  + (size_t)N * 80;         // 20N
        float* fP2 = fh1 + (size_t)N * 20;         // 8N
        float* fo2 = fP2 + (size_t)N * 8;          // 2N
        int*   fbc = (int*)(fo2 + (size_t)N * 2);  // NB (dummy bcur target)
        __half* fxh = (__half*)(fbc + NB);         // 32N words (dummy x_h/h1 targets)
        float* fh1b = (float*)(fxh + (size_t)N * 64);
        const int FB = (E + 255) / 256;
        filter_prep_kernel<<<FB, 256, 0, stream>>>(
            attr, cut, cw1, cb1, f1w1, f1b1, f2w1, f2b1,
            cw2, cb2, f1w2, f1b2, f2w2, f2b2, fw1, fw2, fbc,
            NB <= NB_MAX ? NB : NB_MAX, E,
            x, rt1, bs1, fh1b, fxh, N, FB);
        node_prep1<<<(N + 7) / 8, 256, 0, stream>>>(x, rt1, th1, bs1, fh1, P1, N);
        edge_scatter1<<<(E + 255) / 256, 256, 0, stream>>>(
            ei, (const float4*)fw1, (const float4*)P1, fh1, E);
        node_prep2<<<(N + 255) / 256, 256, 0, stream>>>(fh1, rt2, th2, bs2, fo2, fP2, N);
        edge_scatter2<<<(E + 255) / 256, 256, 0, stream>>>(
            ei, (const float4*)fw2, (const float4*)fP2, fo2, E);
        logsoftmax_k<<<(N + 255) / 256, 256, 0, stream>>>(fo2, (float*)d_out, N);
    }
}